// Round 1
// baseline (2255.597 us; speedup 1.0000x reference)
//
#include <hip/hip_runtime.h>

#define N0_SRC 495616
#define N0_DST 45056
#define E0 450560
#define N1_DST 4096
#define E1 40960
#define IN_FEATS 256
#define NH 128
#define NC 16

// ---------------- Layer 0 edge scatter: agg0 += w*x[src], deg0 += w ----------------
// 64 threads per edge, float4 per lane (64*4 = 256 feats).
__global__ void edge0_kernel(const float* __restrict__ x,
                             const int* __restrict__ src, const int* __restrict__ dst,
                             const float* __restrict__ w,
                             float* __restrict__ agg, float* __restrict__ deg) {
    int t = blockIdx.x * blockDim.x + threadIdx.x;
    int e = t >> 6;
    int lane = t & 63;
    if (e >= E0) return;
    int s = src[e], d = dst[e];
    float we = w[e];
    float4 v = ((const float4*)(x + (size_t)s * IN_FEATS))[lane];
    float* ad = agg + (size_t)d * IN_FEATS + lane * 4;
    unsafeAtomicAdd(ad + 0, v.x * we);
    unsafeAtomicAdd(ad + 1, v.y * we);
    unsafeAtomicAdd(ad + 2, v.z * we);
    unsafeAtomicAdd(ad + 3, v.w * we);
    if (lane == 0) unsafeAtomicAdd(deg + d, we);
}

// ---------------- Layer 0 dense: h0 = relu(((agg + x_dst)/(deg+1)) @ Wn0^T + bn0) ----
// 128 threads (one per output col), 8 nodes per block staged in LDS.
__global__ void __launch_bounds__(128) gemm0_kernel(const float* __restrict__ x,
    const float* __restrict__ agg, const float* __restrict__ deg,
    const float* __restrict__ Wn, const float* __restrict__ bn,
    float* __restrict__ h0) {
    __shared__ float hn[8][IN_FEATS];
    int nb = blockIdx.x * 8;
    int tid = threadIdx.x;
    for (int i = tid; i < 8 * IN_FEATS; i += 128) {
        int n = i >> 8;
        int k = i & 255;
        int m = nb + n;
        float hv = agg[(size_t)m * IN_FEATS + k] + x[(size_t)m * IN_FEATS + k];
        hn[n][k] = hv / (deg[m] + 1.0f);
    }
    __syncthreads();
    float acc[8];
#pragma unroll
    for (int n = 0; n < 8; n++) acc[n] = 0.f;
    const float4* wr4 = (const float4*)(Wn + (size_t)tid * IN_FEATS);
#pragma unroll 4
    for (int k4 = 0; k4 < IN_FEATS / 4; k4++) {
        float4 wv = wr4[k4];
        int k = k4 * 4;
#pragma unroll
        for (int n = 0; n < 8; n++) {
            acc[n] += hn[n][k + 0] * wv.x;
            acc[n] += hn[n][k + 1] * wv.y;
            acc[n] += hn[n][k + 2] * wv.z;
            acc[n] += hn[n][k + 3] * wv.w;
        }
    }
    float b = bn[tid];
#pragma unroll
    for (int n = 0; n < 8; n++) {
        float v = acc[n] + b;
        h0[(size_t)(nb + n) * NH + tid] = v > 0.f ? v : 0.f;
    }
}

// ---------------- Layer 1 edge scatter: 32 threads per edge (32*4 = 128 feats) ------
__global__ void edge1_kernel(const float* __restrict__ h0,
                             const int* __restrict__ src, const int* __restrict__ dst,
                             const float* __restrict__ w,
                             float* __restrict__ agg, float* __restrict__ deg) {
    int t = blockIdx.x * blockDim.x + threadIdx.x;
    int e = t >> 5;
    int lane = t & 31;
    if (e >= E1) return;
    int s = src[e], d = dst[e];
    float we = w[e];
    float4 v = ((const float4*)(h0 + (size_t)s * NH))[lane];
    float* ad = agg + (size_t)d * NH + lane * 4;
    unsafeAtomicAdd(ad + 0, v.x * we);
    unsafeAtomicAdd(ad + 1, v.y * we);
    unsafeAtomicAdd(ad + 2, v.z * we);
    unsafeAtomicAdd(ad + 3, v.w * we);
    if (lane == 0) unsafeAtomicAdd(deg + d, we);
}

// ---------------- Layer 1 dense: h1 = relu(((agg1 + h0_dst)/(deg+1)) @ Wn1^T + bn1) --
__global__ void __launch_bounds__(128) gemm1_kernel(const float* __restrict__ h0,
    const float* __restrict__ agg, const float* __restrict__ deg,
    const float* __restrict__ Wn, const float* __restrict__ bn,
    float* __restrict__ h1) {
    __shared__ float hn[8][NH];
    int nb = blockIdx.x * 8;
    int tid = threadIdx.x;
    for (int i = tid; i < 8 * NH; i += 128) {
        int n = i >> 7;
        int k = i & 127;
        int m = nb + n;
        float hv = agg[(size_t)m * NH + k] + h0[(size_t)m * NH + k];
        hn[n][k] = hv / (deg[m] + 1.0f);
    }
    __syncthreads();
    float acc[8];
#pragma unroll
    for (int n = 0; n < 8; n++) acc[n] = 0.f;
    const float4* wr4 = (const float4*)(Wn + (size_t)tid * NH);
#pragma unroll 4
    for (int k4 = 0; k4 < NH / 4; k4++) {
        float4 wv = wr4[k4];
        int k = k4 * 4;
#pragma unroll
        for (int n = 0; n < 8; n++) {
            acc[n] += hn[n][k + 0] * wv.x;
            acc[n] += hn[n][k + 1] * wv.y;
            acc[n] += hn[n][k + 2] * wv.z;
            acc[n] += hn[n][k + 3] * wv.w;
        }
    }
    float b = bn[tid];
#pragma unroll
    for (int n = 0; n < 8; n++) {
        float v = acc[n] + b;
        h1[(size_t)(nb + n) * NH + tid] = v > 0.f ? v : 0.f;
    }
}

// ---------------- Final FC: out = h1 @ Wfc^T + bfc  (4096 x 16) ---------------------
__global__ void fc_kernel(const float* __restrict__ h1, const float* __restrict__ Wfc,
                          const float* __restrict__ bfc, float* __restrict__ out) {
    int t = blockIdx.x * blockDim.x + threadIdx.x;
    int m = t >> 4, c = t & 15;
    if (m >= N1_DST) return;
    const float* hr = h1 + (size_t)m * NH;
    const float* wr = Wfc + (size_t)c * NH;
    float acc = 0.f;
    for (int k = 0; k < NH; k++) acc += hr[k] * wr[k];
    out[t] = acc + bfc[c];
}

extern "C" void kernel_launch(void* const* d_in, const int* in_sizes, int n_in,
                              void* d_out, int out_size, void* d_ws, size_t ws_size,
                              hipStream_t stream) {
    const float* x   = (const float*)d_in[0];
    const int* src0  = (const int*)d_in[1];
    const int* dst0  = (const int*)d_in[2];
    const float* w0  = (const float*)d_in[3];
    const int* src1  = (const int*)d_in[4];
    const int* dst1  = (const int*)d_in[5];
    const float* w1  = (const float*)d_in[6];
    const float* Wn0 = (const float*)d_in[7];
    const float* bn0 = (const float*)d_in[8];
    const float* Wn1 = (const float*)d_in[9];
    const float* bn1 = (const float*)d_in[10];
    const float* Wfc = (const float*)d_in[11];
    const float* bfc = (const float*)d_in[12];
    float* out = (float*)d_out;

    // workspace layout (floats)
    float* ws = (float*)d_ws;
    float* agg0 = ws;                                   // 45056*256 = 11534336
    float* deg0 = agg0 + (size_t)N0_DST * IN_FEATS;     // 45056
    float* agg1 = deg0 + N0_DST;                        // 4096*128 = 524288
    float* deg1 = agg1 + (size_t)N1_DST * NH;           // 4096
    float* h0   = deg1 + N1_DST;                        // 45056*128
    float* h1   = h0 + (size_t)N0_DST * NH;             // 4096*128
    size_t zero_floats = (size_t)N0_DST * IN_FEATS + N0_DST + (size_t)N1_DST * NH + N1_DST;
    hipMemsetAsync(d_ws, 0, zero_floats * sizeof(float), stream);

    // layer 0
    {
        int threads = 256;
        int blocks = (E0 * 64) / threads;               // 112640
        edge0_kernel<<<blocks, threads, 0, stream>>>(x, src0, dst0, w0, agg0, deg0);
        gemm0_kernel<<<N0_DST / 8, 128, 0, stream>>>(x, agg0, deg0, Wn0, bn0, h0);
    }
    // layer 1
    {
        int threads = 256;
        int blocks = (E1 * 32) / threads;               // 5120
        edge1_kernel<<<blocks, threads, 0, stream>>>(h0, src1, dst1, w1, agg1, deg1);
        gemm1_kernel<<<N1_DST / 8, 128, 0, stream>>>(h0, agg1, deg1, Wn1, bn1, h1);
    }
    // fc
    fc_kernel<<<(N1_DST * NC) / 256, 256, 0, stream>>>(h1, Wfc, bfc, out);
}

// Round 2
// 955.455 us; speedup vs baseline: 2.3608x; 2.3608x over previous
//
#include <hip/hip_runtime.h>

#define N0_SRC 495616
#define N0_DST 45056
#define E0 450560
#define N1_DST 4096
#define E1 40960
#define IN_FEATS 256
#define NH 128
#define NC 16

// ===================== CSR build for layer 0 =====================
__global__ void hist_kernel(const int* __restrict__ dst, int* __restrict__ cnt) {
    int e = blockIdx.x * blockDim.x + threadIdx.x;
    if (e < E0) atomicAdd(&cnt[dst[e]], 1);
}

// Single block, 1024 threads. cnt (45056) -> exclusive prefix into row_start and
// cursor (cnt overwritten in place as the scatter cursor).
__global__ void __launch_bounds__(1024) scan_kernel(int* __restrict__ cnt,
                                                    int* __restrict__ row_start) {
    __shared__ int partial[1024];
    const int CH = N0_DST / 1024;  // 44
    int t = threadIdx.x;
    int base = t * CH;
    int s = 0;
    for (int j = 0; j < CH; j++) s += cnt[base + j];
    partial[t] = s;
    __syncthreads();
    for (int off = 1; off < 1024; off <<= 1) {
        int v = (t >= off) ? partial[t - off] : 0;
        __syncthreads();
        partial[t] += v;
        __syncthreads();
    }
    int run = partial[t] - s;  // exclusive prefix of this thread's chunk
    for (int j = 0; j < CH; j++) {
        int c = cnt[base + j];
        row_start[base + j] = run;
        cnt[base + j] = run;   // cursor starts at row offset
        run += c;
    }
    if (t == 1023) row_start[N0_DST] = run;  // == E0
}

__global__ void scatter_kernel(const int* __restrict__ dst, int* __restrict__ cursor,
                               int* __restrict__ perm) {
    int e = blockIdx.x * blockDim.x + threadIdx.x;
    if (e < E0) {
        int p = atomicAdd(&cursor[dst[e]], 1);
        perm[p] = e;
    }
}

// ===================== Layer 0 aggregate (gather-only) =====================
// One wave (64 lanes) per dst node; float4 per lane = 256 feats in registers.
// Writes h_neigh = (sum w_e * x[src_e] + x_dst) / (deg + 1) exactly once.
__global__ void __launch_bounds__(256) agg0_kernel(const float* __restrict__ x,
    const int* __restrict__ src0, const float* __restrict__ w0,
    const int* __restrict__ perm, const int* __restrict__ row_start,
    float* __restrict__ hneigh) {
    int wv = blockIdx.x * 4 + (threadIdx.x >> 6);
    int lane = threadIdx.x & 63;
    if (wv >= N0_DST) return;
    int beg = row_start[wv], end = row_start[wv + 1];
    const float4* x4 = (const float4*)x;
    float4 acc = make_float4(0.f, 0.f, 0.f, 0.f);
    float degs = 0.f;
    // prefetch-1 pipeline to break the perm->src->row dependent-latency chain
    int s = 0; float we = 0.f;
    if (beg < end) { int e = perm[beg]; s = src0[e]; we = w0[e]; }
    for (int i = beg; i < end; i++) {
        int s2 = 0; float we2 = 0.f;
        if (i + 1 < end) { int e2 = perm[i + 1]; s2 = src0[e2]; we2 = w0[e2]; }
        float4 v = x4[(size_t)s * 64 + lane];
        acc.x += we * v.x; acc.y += we * v.y; acc.z += we * v.z; acc.w += we * v.w;
        degs += we;
        s = s2; we = we2;
    }
    float4 xd = x4[(size_t)wv * 64 + lane];
    float inv = 1.0f / (degs + 1.0f);
    float4 r;
    r.x = (acc.x + xd.x) * inv; r.y = (acc.y + xd.y) * inv;
    r.z = (acc.z + xd.z) * inv; r.w = (acc.w + xd.w) * inv;
    ((float4*)hneigh)[(size_t)wv * 64 + lane] = r;
}

// ===================== Layer 0 dense: h0 = relu(hneigh @ Wn0^T + bn0) ========
__global__ void __launch_bounds__(128) gemm0_kernel(const float* __restrict__ hneigh,
    const float* __restrict__ Wn, const float* __restrict__ bn,
    float* __restrict__ h0) {
    __shared__ float hn[8][IN_FEATS];
    int nb = blockIdx.x * 8;
    int tid = threadIdx.x;
    for (int i = tid; i < 8 * IN_FEATS; i += 128) {
        int n = i >> 8;
        int k = i & 255;
        hn[n][k] = hneigh[(size_t)(nb + n) * IN_FEATS + k];
    }
    __syncthreads();
    float acc[8];
#pragma unroll
    for (int n = 0; n < 8; n++) acc[n] = 0.f;
    const float4* wr4 = (const float4*)(Wn + (size_t)tid * IN_FEATS);
#pragma unroll 4
    for (int k4 = 0; k4 < IN_FEATS / 4; k4++) {
        float4 wv = wr4[k4];
        int k = k4 * 4;
#pragma unroll
        for (int n = 0; n < 8; n++) {
            acc[n] += hn[n][k + 0] * wv.x;
            acc[n] += hn[n][k + 1] * wv.y;
            acc[n] += hn[n][k + 2] * wv.z;
            acc[n] += hn[n][k + 3] * wv.w;
        }
    }
    float b = bn[tid];
#pragma unroll
    for (int n = 0; n < 8; n++) {
        float v = acc[n] + b;
        h0[(size_t)(nb + n) * NH + tid] = v > 0.f ? v : 0.f;
    }
}

// ===================== Layer 1 edge scatter (agg1 is 2 MB -> L2-resident) ====
__global__ void edge1_kernel(const float* __restrict__ h0,
                             const int* __restrict__ src, const int* __restrict__ dst,
                             const float* __restrict__ w,
                             float* __restrict__ agg, float* __restrict__ deg) {
    int t = blockIdx.x * blockDim.x + threadIdx.x;
    int e = t >> 5;
    int lane = t & 31;
    if (e >= E1) return;
    int s = src[e], d = dst[e];
    float we = w[e];
    float4 v = ((const float4*)(h0 + (size_t)s * NH))[lane];
    float* ad = agg + (size_t)d * NH + lane * 4;
    unsafeAtomicAdd(ad + 0, v.x * we);
    unsafeAtomicAdd(ad + 1, v.y * we);
    unsafeAtomicAdd(ad + 2, v.z * we);
    unsafeAtomicAdd(ad + 3, v.w * we);
    if (lane == 0) unsafeAtomicAdd(deg + d, we);
}

// ===================== Layer 1 dense ========================================
__global__ void __launch_bounds__(128) gemm1_kernel(const float* __restrict__ h0,
    const float* __restrict__ agg, const float* __restrict__ deg,
    const float* __restrict__ Wn, const float* __restrict__ bn,
    float* __restrict__ h1) {
    __shared__ float hn[8][NH];
    int nb = blockIdx.x * 8;
    int tid = threadIdx.x;
    for (int i = tid; i < 8 * NH; i += 128) {
        int n = i >> 7;
        int k = i & 127;
        int m = nb + n;
        float hv = agg[(size_t)m * NH + k] + h0[(size_t)m * NH + k];
        hn[n][k] = hv / (deg[m] + 1.0f);
    }
    __syncthreads();
    float acc[8];
#pragma unroll
    for (int n = 0; n < 8; n++) acc[n] = 0.f;
    const float4* wr4 = (const float4*)(Wn + (size_t)tid * NH);
#pragma unroll 4
    for (int k4 = 0; k4 < NH / 4; k4++) {
        float4 wv = wr4[k4];
        int k = k4 * 4;
#pragma unroll
        for (int n = 0; n < 8; n++) {
            acc[n] += hn[n][k + 0] * wv.x;
            acc[n] += hn[n][k + 1] * wv.y;
            acc[n] += hn[n][k + 2] * wv.z;
            acc[n] += hn[n][k + 3] * wv.w;
        }
    }
    float b = bn[tid];
#pragma unroll
    for (int n = 0; n < 8; n++) {
        float v = acc[n] + b;
        h1[(size_t)(nb + n) * NH + tid] = v > 0.f ? v : 0.f;
    }
}

// ===================== Final FC =============================================
__global__ void fc_kernel(const float* __restrict__ h1, const float* __restrict__ Wfc,
                          const float* __restrict__ bfc, float* __restrict__ out) {
    int t = blockIdx.x * blockDim.x + threadIdx.x;
    int m = t >> 4, c = t & 15;
    if (m >= N1_DST) return;
    const float* hr = h1 + (size_t)m * NH;
    const float* wr = Wfc + (size_t)c * NH;
    float acc = 0.f;
    for (int k = 0; k < NH; k++) acc += hr[k] * wr[k];
    out[t] = acc + bfc[c];
}

extern "C" void kernel_launch(void* const* d_in, const int* in_sizes, int n_in,
                              void* d_out, int out_size, void* d_ws, size_t ws_size,
                              hipStream_t stream) {
    const float* x   = (const float*)d_in[0];
    const int* src0  = (const int*)d_in[1];
    const int* dst0  = (const int*)d_in[2];
    const float* w0  = (const float*)d_in[3];
    const int* src1  = (const int*)d_in[4];
    const int* dst1  = (const int*)d_in[5];
    const float* w1  = (const float*)d_in[6];
    const float* Wn0 = (const float*)d_in[7];
    const float* bn0 = (const float*)d_in[8];
    const float* Wn1 = (const float*)d_in[9];
    const float* bn1 = (const float*)d_in[10];
    const float* Wfc = (const float*)d_in[11];
    const float* bfc = (const float*)d_in[12];
    float* out = (float*)d_out;

    // workspace layout (4-byte units). Total 18370561 floats = 73.5 MB.
    float* ws = (float*)d_ws;
    float* agg1      = ws;                           // 524288
    float* deg1      = agg1 + (size_t)N1_DST * NH;   // 4096
    int*   cnt       = (int*)(deg1 + N1_DST);        // 45056 (becomes cursor)
    int*   row_start = cnt + N0_DST;                 // 45057
    int*   perm      = row_start + N0_DST + 1;       // 450560
    float* hneigh    = (float*)(perm + E0);          // 11534336
    float* h0        = hneigh + (size_t)N0_DST * IN_FEATS; // 5767168
    float* h1        = (float*)cnt;                  // 524288, reuses cnt/row_start/perm
                                                     // (consumed before gemm1 runs)

    // zero agg1 + deg1 + cnt in one shot (contiguous)
    size_t zero_floats = (size_t)N1_DST * NH + N1_DST + N0_DST;
    hipMemsetAsync(d_ws, 0, zero_floats * sizeof(float), stream);

    // CSR build for layer 0
    hist_kernel<<<(E0 + 255) / 256, 256, 0, stream>>>(dst0, cnt);
    scan_kernel<<<1, 1024, 0, stream>>>(cnt, row_start);
    scatter_kernel<<<(E0 + 255) / 256, 256, 0, stream>>>(dst0, cnt, perm);

    // layer 0: gather-aggregate, then dense
    agg0_kernel<<<(N0_DST + 3) / 4, 256, 0, stream>>>(x, src0, w0, perm, row_start, hneigh);
    gemm0_kernel<<<N0_DST / 8, 128, 0, stream>>>(hneigh, Wn0, bn0, h0);

    // layer 1
    edge1_kernel<<<(E1 * 32) / 256, 256, 0, stream>>>(h0, src1, dst1, w1, agg1, deg1);
    gemm1_kernel<<<N1_DST / 8, 128, 0, stream>>>(h0, agg1, deg1, Wn1, bn1, h1);

    // fc
    fc_kernel<<<(N1_DST * NC) / 256, 256, 0, stream>>>(h1, Wfc, bfc, out);
}